// Round 12
// baseline (401.809 us; speedup 1.0000x reference)
//
#include <hip/hip_runtime.h>
#include <math.h>

#define S 512
#define B 128
#define T 256
#define NTH 256
#define LOG2E 1.44269504f
#define LN2 0.69314718f

typedef _Float16 h2 __attribute__((ext_vector_type(2)));

#if __has_builtin(__builtin_amdgcn_fdot2)
#define FDOT2(a, b, c) __builtin_amdgcn_fdot2((a), (b), (c), false)
#else
#define FDOT2(a, b, c) fmaf((float)(a)[0], (float)(b)[0], fmaf((float)(a)[1], (float)(b)[1], (c)))
#endif

#if __has_builtin(__builtin_amdgcn_exp2f)
#define EXP2(x) __builtin_amdgcn_exp2f(x)
#else
#define EXP2(x) exp2f(x)
#endif
#if __has_builtin(__builtin_amdgcn_logf)
#define LOG2F(x) __builtin_amdgcn_logf(x)
#else
#define LOG2F(x) __log2f(x)
#endif

#define AS1 __attribute__((address_space(1)))
#define AS3 __attribute__((address_space(3)))

// LDS-drain barrier only (DMA ring stays in flight; counted vmcnt separately)
#define BAR() do { asm volatile("s_waitcnt lgkmcnt(0)" ::: "memory"); __builtin_amdgcn_s_barrier(); } while (0)

// exact x * 2^n (n in [-126,127])
__device__ __forceinline__ float mul2n(float x, int n) {
    return x * __builtin_bit_cast(float, (n + 127) << 23);
}

template<int CTRL, int RM>
__device__ __forceinline__ float dppmax(float x) {
    int xi = __builtin_bit_cast(int, x);
    int yi = __builtin_amdgcn_update_dpp(xi, xi, CTRL, RM, 0xf, false);
    return fmaxf(x, __builtin_bit_cast(float, yi));
}
__device__ __forceinline__ float wave_max64(float x) {
    x = dppmax<0x111, 0xf>(x);  // row_shr:1
    x = dppmax<0x112, 0xf>(x);  // row_shr:2
    x = dppmax<0x114, 0xf>(x);  // row_shr:4
    x = dppmax<0x118, 0xf>(x);  // row_shr:8
    x = dppmax<0x142, 0xa>(x);  // row_bcast:15
    x = dppmax<0x143, 0xc>(x);  // row_bcast:31
    return __builtin_bit_cast(float, __builtin_amdgcn_readlane(__builtin_bit_cast(int, x), 63));
}

__global__ __launch_bounds__(NTH, 1) void crf_fwd(
    const float* __restrict__ feats,
    const int*   __restrict__ tags,
    const int*   __restrict__ mask,
    const float* __restrict__ start_t,
    const float* __restrict__ end_t,
    const float* __restrict__ trans,
    float*       __restrict__ out)
{
    const int b    = blockIdx.x;
    const int j    = threadIdx.x;     // owned OUTPUT column 0..255
    const int lane = j & 63;
    const int w    = j >> 6;          // wave 0..3

    __shared__ __attribute__((aligned(16))) _Float16 qbuf[2][T];  // packed state, ping-pong (1 KB)
    __shared__ float ftile[8][T];                                 // feats DMA ring (8 KB)
    __shared__ int   msk[S];
    __shared__ __attribute__((aligned(16))) float redq[2][4];     // per-wave q max, ping-pong
    __shared__ float redF[4], redS[4], redg[4], redm[4], redi[4];

    // ---- prime DMA ring with feats tiles t=1..4 (each wave loads its own quarter)
    #pragma unroll
    for (int tn = 1; tn <= 4; ++tn) {
        const float* src = feats + ((size_t)tn * B + b) * T + j;
        __builtin_amdgcn_global_load_lds((const AS1 void*)src,
                                         (AS3 void*)&ftile[tn & 7][j], 4, 0, 0);
    }

    // ---- small per-thread loads
    const float endj = end_t[j];
    const float sc0  = start_t[j] + feats[(size_t)b * T + j];   // score at t=0
    msk[j]     = mask[j * B + b];
    msk[j + T] = mask[(j + T) * B + b];

    // ---- gold-score terms: two time steps per thread
    float gterm = 0.f, mcnt = 0.f;
    #pragma unroll
    for (int c = 0; c < 2; ++c) {
        const int t  = j + c * T;
        const int tg = tags[t * B + b];
        const int m  = mask[t * B + b];
        const float emit = feats[((size_t)t * B + b) * T + tg];
        mcnt += (float)m;
        if (t == 0) gterm += start_t[tg] + emit;
        else        gterm += m ? (emit + trans[tags[(t - 1) * B + b] * T + tg]) : 0.f;
    }
    #pragma unroll
    for (int o = 32; o > 0; o >>= 1) {
        gterm += __shfl_down(gterm, o, 64);
        mcnt  += __shfl_down(mcnt, o, 64);
    }
    if (lane == 0) { redg[w] = gterm; redm[w] = mcnt; }

    // ---- E column in registers: E2[p] = (exp(trans[2p][j]), exp(trans[2p+1][j])) fp16 (RTN)
    h2 E2[128];
    {
        const float* tc = trans + j;
        #pragma unroll
        for (int p = 0; p < 128; ++p) {
            const float e0 = EXP2(LOG2E * tc[(size_t)(2 * p) * T]);
            const float e1 = EXP2(LOG2E * tc[(size_t)(2 * p + 1) * T]);
            h2 v; v[0] = (_Float16)e0; v[1] = (_Float16)e1;
            E2[p] = v;
        }
    }

    // ---- init global exponent A from block max of sc0
    {
        const float mx = wave_max64(sc0);
        if (lane == 0) redi[w] = mx;
    }
    __syncthreads();   // full drain once (init; primed tiles 1..4 landed)

    float gold = 0.f;
    if (j == 0) {
        const float g  = redg[0] + redg[1] + redg[2] + redg[3];
        const float mc = redm[0] + redm[1] + redm[2] + redm[3];
        gold = g + end_t[tags[((int)mc - 1) * B + b]];
    }

    const float gmax0 = fmaxf(fmaxf(redi[0], redi[1]), fmaxf(redi[2], redi[3]));
    int A = (int)ceilf(gmax0 * LOG2E) + 10;
    float q = EXP2(fmaf(sc0, LOG2E, (float)(-A)));   // max(q) ~= 2^-10
    qbuf[0][j] = (_Float16)q;                        // RTN pack
    {
        const float mq = wave_max64(q);
        if (lane == 0) redq[0][w] = mq;
    }
    float Fnext = EXP2(ftile[1][j] * LOG2E);         // F(1), off the recursion path
    __syncthreads();   // qbuf[0]/redq[0] visible

    for (int t = 1; t < S; ++t) {
        const int cur = (t - 1) & 1;
        const float Fcur = Fnext;

        // ---- early LDS reads (issue right after the barrier)
        const float4 rq = *(const float4*)&redq[cur][0];        // broadcast
        const int2 qp   = *(const int2*)&qbuf[cur][4 * lane];   // own 2 q-pairs (b64)
        const int mskt  = msk[t];

        // ---- DMA prefetch t+4 (8-slot ring), counted wait: tile t+1 landed
        if (t + 4 < S) {
            const float* src = feats + ((size_t)(t + 4) * B + b) * T + j;
            __builtin_amdgcn_global_load_lds((const AS1 void*)src,
                                             (AS3 void*)&ftile[(t + 4) & 7][j], 4, 0, 0);
            asm volatile("s_waitcnt vmcnt(3)" ::: "memory");
        } else if (t == S - 4) { asm volatile("s_waitcnt vmcnt(2)" ::: "memory"); }
        else if   (t == S - 3) { asm volatile("s_waitcnt vmcnt(1)" ::: "memory"); }
        else if   (t == S - 2) { asm volatile("s_waitcnt vmcnt(0)" ::: "memory"); }
        const float ftn = (t < S - 1) ? ftile[(t + 1) & 7][j] : 0.f;

        // ---- GEMV for own column: full 256 rows via readlane broadcasts (no LDS pressure)
        // pair p = (q[2p], q[2p+1]) lives in lane p>>1, reg (p&1 ? y : x)
        float a0 = 0.f, a1 = 0.f, a2 = 0.f, a3 = 0.f;
        int pr = __builtin_amdgcn_readlane(qp.x, 0);
        #pragma unroll
        for (int p = 0; p < 128; ++p) {
            const int prn = (p < 127)
                ? __builtin_amdgcn_readlane((p & 1) ? qp.x : qp.y, (p + 1) >> 1)
                : 0;
            const h2 pv = __builtin_bit_cast(h2, pr);
            if ((p & 3) == 0)      a0 = FDOT2(E2[p], pv, a0);
            else if ((p & 3) == 1) a1 = FDOT2(E2[p], pv, a1);
            else if ((p & 3) == 2) a2 = FDOT2(E2[p], pv, a2);
            else                   a3 = FDOT2(E2[p], pv, a3);
            pr = prn;
        }
        const float s = (a0 + a1) + (a2 + a3);

        // ---- scale + update (k from previous step's block max; global exponent A)
        const float gm = fmaxf(fmaxf(rq.x, rq.y), fmaxf(rq.z, rq.w));
        const int k = ((__builtin_bit_cast(int, gm) >> 23) & 0xff) - 117;  // floor(log2 gm)+10
        const float s2k = __builtin_bit_cast(float, (127 - k) << 23);      // 2^-k exact
        const float qn = s * (Fcur * s2k);
        const float qf = mul2n(q, -k);                 // frozen path (mask=0), exact
        q = mskt ? qn : qf;
        A += k;
        qbuf[t & 1][j] = (_Float16)q;                  // RTN pack, ping-pong
        Fnext = EXP2(ftn * LOG2E);                     // F(t+1), off-path
        {
            const float mq = wave_max64(q);            // for next step's k
            if (lane == 0) redq[t & 1][w] = mq;
        }
        BAR();   // the only barrier per step
    }

    // ---- finalize: score_j = (log2 q + A)*ln2; forward = LSE(score + end)
    const float u2 = LOG2F(q) + (float)A + endj * LOG2E;
    {
        const float mw = wave_max64(u2);
        if (lane == 0) redF[w] = mw;
    }
    BAR();
    {
        const float gmax = fmaxf(fmaxf(redF[0], redF[1]), fmaxf(redF[2], redF[3]));
        float e = EXP2(u2 - gmax);
        #pragma unroll
        for (int o = 32; o > 0; o >>= 1) e += __shfl_xor(e, o, 64);
        if (lane == 0) redS[w] = e;
        BAR();
        if (j == 0) {
            const float ssum = redS[0] + redS[1] + redS[2] + redS[3];
            out[b] = (gmax + LOG2F(ssum)) * LN2 - gold;
        }
    }
}

extern "C" void kernel_launch(void* const* d_in, const int* in_sizes, int n_in,
                              void* d_out, int out_size, void* d_ws, size_t ws_size,
                              hipStream_t stream) {
    const float* feats  = (const float*)d_in[0];
    const int*   tags   = (const int*)d_in[1];
    const int*   mask   = (const int*)d_in[2];
    const float* startt = (const float*)d_in[3];
    const float* endt   = (const float*)d_in[4];
    const float* transt = (const float*)d_in[5];
    float* out = (float*)d_out;
    crf_fwd<<<dim3(B), dim3(NTH), 0, stream>>>(feats, tags, mask, startt, endt, transt, out);
}

// Round 13
// 352.106 us; speedup vs baseline: 1.1412x; 1.1412x over previous
//
#include <hip/hip_runtime.h>
#include <math.h>

#define S 512
#define B 128
#define T 256
#define NTH 256
#define LOG2E 1.44269504f
#define LN2 0.69314718f

typedef _Float16 h2 __attribute__((ext_vector_type(2)));

#if __has_builtin(__builtin_amdgcn_fdot2)
#define FDOT2(a, b, c) __builtin_amdgcn_fdot2((a), (b), (c), false)
#else
#define FDOT2(a, b, c) fmaf((float)(a)[0], (float)(b)[0], fmaf((float)(a)[1], (float)(b)[1], (c)))
#endif

#if __has_builtin(__builtin_amdgcn_exp2f)
#define EXP2(x) __builtin_amdgcn_exp2f(x)
#else
#define EXP2(x) exp2f(x)
#endif
#if __has_builtin(__builtin_amdgcn_logf)
#define LOG2F(x) __builtin_amdgcn_logf(x)
#else
#define LOG2F(x) __log2f(x)
#endif

#define AS1 __attribute__((address_space(1)))
#define AS3 __attribute__((address_space(3)))

// LDS-drain barrier only (DMA ring stays in flight; counted vmcnt separately)
#define BAR() do { asm volatile("s_waitcnt lgkmcnt(0)" ::: "memory"); __builtin_amdgcn_s_barrier(); } while (0)

// exact x * 2^n (n in [-126,127])
__device__ __forceinline__ float mul2n(float x, int n) {
    return x * __builtin_bit_cast(float, (n + 127) << 23);
}

template<int CTRL, int RM>
__device__ __forceinline__ float dppmax(float x) {
    int xi = __builtin_bit_cast(int, x);
    int yi = __builtin_amdgcn_update_dpp(xi, xi, CTRL, RM, 0xf, false);
    return fmaxf(x, __builtin_bit_cast(float, yi));
}
__device__ __forceinline__ float wave_max64(float x) {
    x = dppmax<0x111, 0xf>(x);  // row_shr:1
    x = dppmax<0x112, 0xf>(x);  // row_shr:2
    x = dppmax<0x114, 0xf>(x);  // row_shr:4
    x = dppmax<0x118, 0xf>(x);  // row_shr:8
    x = dppmax<0x142, 0xa>(x);  // row_bcast:15
    x = dppmax<0x143, 0xc>(x);  // row_bcast:31
    return __builtin_bit_cast(float, __builtin_amdgcn_readlane(__builtin_bit_cast(int, x), 63));
}
// lane gets lane|1's value within each quad (sel [1,1,3,3] -> 0xF5)
__device__ __forceinline__ float quad_next(float x) {
    int xi = __builtin_bit_cast(int, x);
    int yi = __builtin_amdgcn_update_dpp(xi, xi, 0xF5, 0xf, 0xf, false);
    return __builtin_bit_cast(float, yi);
}

__global__ __launch_bounds__(NTH, 1) void crf_fwd(
    const float* __restrict__ feats,
    const int*   __restrict__ tags,
    const int*   __restrict__ mask,
    const float* __restrict__ start_t,
    const float* __restrict__ end_t,
    const float* __restrict__ trans,
    float*       __restrict__ out)
{
    const int b    = blockIdx.x;
    const int j    = threadIdx.x;     // owned state column 0..255
    const int lane = j & 63;
    const int w    = j >> 6;          // wave 0..3 (GEMV rows [64w,64w+64))

    __shared__ __attribute__((aligned(16))) float part[2][4][T];  // partials, ping-pong (8 KB)
    __shared__ float ftile[8][T];                                 // feats DMA ring (8 KB)
    __shared__ int   msk[S];
    __shared__ __attribute__((aligned(16))) float redq[2][4];     // per-wave q max, ping-pong
    __shared__ float redF[4], redS[4], redg[4], redm[4], redi[4];

    // ---- prime DMA ring with feats tiles t=1..4
    #pragma unroll
    for (int tn = 1; tn <= 4; ++tn) {
        const float* src = feats + ((size_t)tn * B + b) * T + j;
        __builtin_amdgcn_global_load_lds((const AS1 void*)src,
                                         (AS3 void*)&ftile[tn & 7][j], 4, 0, 0);
    }

    // ---- small per-thread loads
    const float endj = end_t[j];
    const float sc0  = start_t[j] + feats[(size_t)b * T + j];   // score at t=0
    msk[j]     = mask[j * B + b];
    msk[j + T] = mask[(j + T) * B + b];

    // ---- gold-score terms: two time steps per thread
    float gterm = 0.f, mcnt = 0.f;
    #pragma unroll
    for (int c = 0; c < 2; ++c) {
        const int t  = j + c * T;
        const int tg = tags[t * B + b];
        const int m  = mask[t * B + b];
        const float emit = feats[((size_t)t * B + b) * T + tg];
        mcnt += (float)m;
        if (t == 0) gterm += start_t[tg] + emit;
        else        gterm += m ? (emit + trans[tags[(t - 1) * B + b] * T + tg]) : 0.f;
    }
    #pragma unroll
    for (int o = 32; o > 0; o >>= 1) {
        gterm += __shfl_down(gterm, o, 64);
        mcnt  += __shfl_down(mcnt, o, 64);
    }
    if (lane == 0) { redg[w] = gterm; redm[w] = mcnt; }

    // ---- E fragment (RTN packing): rows i in [64w, 64w+64) paired, cols 4*lane..+3
    h2 E2[32][4];
    {
        const float* tp = trans + (size_t)(64 * w) * T + 4 * lane;
        #pragma unroll
        for (int ip = 0; ip < 32; ++ip) {
            const float4 ra = *(const float4*)(tp + (size_t)(2 * ip) * T);
            const float4 rb = *(const float4*)(tp + (size_t)(2 * ip + 1) * T);
            #pragma unroll
            for (int c = 0; c < 4; ++c) {
                const float e0 = EXP2(LOG2E * (c == 0 ? ra.x : c == 1 ? ra.y : c == 2 ? ra.z : ra.w));
                const float e1 = EXP2(LOG2E * (c == 0 ? rb.x : c == 1 ? rb.y : c == 2 ? rb.z : rb.w));
                h2 v; v[0] = (_Float16)e0; v[1] = (_Float16)e1;
                E2[ip][c] = v;
            }
        }
    }

    // ---- init block max of sc0 -> global exponent A
    {
        const float mx = wave_max64(sc0);
        if (lane == 0) redi[w] = mx;
    }
    __syncthreads();   // full drain once (init; primed tiles 1..4 landed)

    float gold = 0.f;
    if (j == 0) {
        const float g  = redg[0] + redg[1] + redg[2] + redg[3];
        const float mc = redm[0] + redm[1] + redm[2] + redm[3];
        gold = g + end_t[tags[((int)mc - 1) * B + b]];
    }

    const float gmax0 = fmaxf(fmaxf(redi[0], redi[1]), fmaxf(redi[2], redi[3]));
    int A = (int)ceilf(gmax0 * LOG2E) + 10;
    float q = EXP2(fmaf(sc0, LOG2E, (float)(-A)));   // max(q) ~= 2^-10
    int pki;
    {
        const float qnb = quad_next(q);
        h2 v; v[0] = (_Float16)q; v[1] = (_Float16)qnb;   // RTN pack
        pki = __builtin_bit_cast(int, v);
    }
    {
        const float mq = wave_max64(q);
        if (lane == 0) redq[0][w] = mq;
    }
    float Fnext = EXP2(ftile[1][j] * LOG2E);         // F(1): exp off the recursion path
    __syncthreads();   // redq[0] visible

    for (int t = 1; t < S; ++t) {
        const int cur = (t - 1) & 1, nxt = t & 1;
        const float Fcur = Fnext;

        // ---- GEMV over own wave's 64 rows (q pairs broadcast via readlane of own lanes)
        float ax = 0.f, ay = 0.f, az = 0.f, aw = 0.f;
        int pr0 = __builtin_amdgcn_readlane(pki, 0);
        #pragma unroll
        for (int ip = 0; ip < 32; ++ip) {
            const int pr1 = (ip < 31) ? __builtin_amdgcn_readlane(pki, 2 * ip + 2) : 0;
            const h2 pp = __builtin_bit_cast(h2, pr0);
            ax = FDOT2(E2[ip][0], pp, ax);
            ay = FDOT2(E2[ip][1], pp, ay);
            az = FDOT2(E2[ip][2], pp, az);
            aw = FDOT2(E2[ip][3], pp, aw);
            pr0 = pr1;
        }
        {
            float4 acc; acc.x = ax; acc.y = ay; acc.z = az; acc.w = aw;
            *(float4*)&part[nxt][w][4 * lane] = acc;
        }
        // ---- DMA ring: prefetch tile t+4 (8-slot ring), counted wait: tile t+1 landed
        if (t <= S - 5) {
            const float* src = feats + ((size_t)(t + 4) * B + b) * T + j;
            __builtin_amdgcn_global_load_lds((const AS1 void*)src,
                                             (AS3 void*)&ftile[(t + 4) & 7][j], 4, 0, 0);
            asm volatile("s_waitcnt vmcnt(3)" ::: "memory");
        } else if (t == S - 4) { asm volatile("s_waitcnt vmcnt(2)" ::: "memory"); }
        else if   (t == S - 3) { asm volatile("s_waitcnt vmcnt(1)" ::: "memory"); }
        else if   (t == S - 2) { asm volatile("s_waitcnt vmcnt(0)" ::: "memory"); }
        BAR();   // the only barrier per step

        // ---- combine: global-k (R8/R12-exact), plain 4-way add, no Aex machinery
        const float4 rq = *(const float4*)&redq[cur][0];   // broadcast b128
        const float s0 = part[nxt][0][j];
        const float s1 = part[nxt][1][j];
        const float s2 = part[nxt][2][j];
        const float s3 = part[nxt][3][j];
        const float ftn = (t < S - 1) ? ftile[(t + 1) & 7][j] : 0.f;
        const int mskt = msk[t];
        const float gm = fmaxf(fmaxf(rq.x, rq.y), fmaxf(rq.z, rq.w));
        const int k = ((__builtin_bit_cast(int, gm) >> 23) & 0xff) - 117;  // floor(log2 gm)+10
        const float s2k = __builtin_bit_cast(float, (127 - k) << 23);      // 2^-k exact
        const float Fs = Fcur * s2k;                    // ready before partials return
        const float cb = (s0 + s1) + (s2 + s3);
        const float qn = cb * Fs;
        const float qf = mul2n(q, -k);                  // frozen path (mask=0), exact
        q = mskt ? qn : qf;
        A += k;
        // pack (RTN) for next GEMV
        {
            const float qnb = quad_next(q);
            h2 v; v[0] = (_Float16)q; v[1] = (_Float16)qnb;
            pki = __builtin_bit_cast(int, v);
        }
        // next-step k + F (independent of next GEMV -> scheduler overlaps them)
        {
            const float mq = wave_max64(q);
            if (lane == 0) redq[nxt][w] = mq;
        }
        Fnext = EXP2(ftn * LOG2E);
    }

    BAR();

    // ---- finalize: score_j = (log2 q + A)*ln2; forward = LSE(score + end)
    const float u2 = LOG2F(q) + (float)A + endj * LOG2E;
    {
        const float mw = wave_max64(u2);
        if (lane == 0) redF[w] = mw;
    }
    BAR();
    {
        const float gmax = fmaxf(fmaxf(redF[0], redF[1]), fmaxf(redF[2], redF[3]));
        float e = EXP2(u2 - gmax);
        #pragma unroll
        for (int o = 32; o > 0; o >>= 1) e += __shfl_xor(e, o, 64);
        if (lane == 0) redS[w] = e;
        BAR();
        if (j == 0) {
            const float ssum = redS[0] + redS[1] + redS[2] + redS[3];
            out[b] = (gmax + LOG2F(ssum)) * LN2 - gold;
        }
    }
}

extern "C" void kernel_launch(void* const* d_in, const int* in_sizes, int n_in,
                              void* d_out, int out_size, void* d_ws, size_t ws_size,
                              hipStream_t stream) {
    const float* feats  = (const float*)d_in[0];
    const int*   tags   = (const int*)d_in[1];
    const int*   mask   = (const int*)d_in[2];
    const float* startt = (const float*)d_in[3];
    const float* endt   = (const float*)d_in[4];
    const float* transt = (const float*)d_in[5];
    float* out = (float*)d_out;
    crf_fwd<<<dim3(B), dim3(NTH), 0, stream>>>(feats, tags, mask, startt, endt, transt, out);
}